// Round 1
// baseline (107.487 us; speedup 1.0000x reference)
//
#include <hip/hip_runtime.h>

// DNM_Linear: out[b,o] = relu(K*(K*S - QS)),  S = sum_{m,i} relu(x[b,i]*W[o,m,i] - q[o,m,i])
// B=128, IN=512, OUT=256, M=16, K=0.5, QS=0.1
//
// Design: 1 block per o (256 blocks = 1/CU). Each thread keeps 32 W + 32 (-q)
// elements in registers (loaded once), loops over all 128 batch rows reading
// one float4 of x per row (L2-resident). Block reduction via padded LDS +
// shfl_xor. Compute-bound on VALU (~10 us floor).

#define B_    128
#define IN_   512
#define OUT_  256
#define M_    16
#define K_    0.5f
#define QS_   0.1f

__global__ __launch_bounds__(256, 1) void dnm_kernel(
    const float* __restrict__ x,
    const float* __restrict__ W,
    const float* __restrict__ q,
    float* __restrict__ out)
{
    const int t = threadIdx.x;
    const int o = blockIdx.x;

    const float4* __restrict__ W4 = reinterpret_cast<const float4*>(W + (size_t)o * (M_ * IN_));
    const float4* __restrict__ Q4 = reinterpret_cast<const float4*>(q + (size_t)o * (M_ * IN_));
    const float4* __restrict__ X4 = reinterpret_cast<const float4*>(x);

    // Thread t owns float4 chunks t + 256*k (k=0..7) of the 2048-float4 W[o]/q[o] panel.
    // Element base of chunk k = 4t + 1024k  ->  i0 = (4t) % 512 = 4*(t & 127) for ALL k.
    float4 w[8], nq[8];
#pragma unroll
    for (int k = 0; k < 8; ++k) {
        w[k] = W4[t + 256 * k];
        float4 qv = Q4[t + 256 * k];
        nq[k] = make_float4(-qv.x, -qv.y, -qv.z, -qv.w);
    }

    __shared__ float red[256][33];   // padded: writes/reads are <=2-way bank aliased (free)
    __shared__ float red2[4][32];

    const int xcol = t & 127;
    const int lane = t & 63;
    const int wv   = t >> 6;

    for (int tile = 0; tile < 4; ++tile) {
        const int b0 = tile * 32;

#pragma unroll 4
        for (int bb = 0; bb < 32; ++bb) {
            float4 xv = X4[(size_t)(b0 + bb) * (IN_ / 4) + xcol];
            float a = 0.f;
#pragma unroll
            for (int k = 0; k < 8; ++k) {
                float z;
                z = fmaf(xv.x, w[k].x, nq[k].x); a += fmaxf(z, 0.f);
                z = fmaf(xv.y, w[k].y, nq[k].y); a += fmaxf(z, 0.f);
                z = fmaf(xv.z, w[k].z, nq[k].z); a += fmaxf(z, 0.f);
                z = fmaf(xv.w, w[k].w, nq[k].w); a += fmaxf(z, 0.f);
            }
            red[t][bb] = a;   // per-thread partial for batch row b0+bb
        }
        __syncthreads();

        // Reduce 256 partials per batch row.
        {
            const int b = t & 31;
            const int g = t >> 5;          // 8 groups of 32 source threads
            float s = 0.f;
#pragma unroll
            for (int j = 0; j < 32; ++j) s += red[g * 32 + j][b];
            s += __shfl_xor(s, 32);        // combine the two groups within each wave
            if (lane < 32) red2[wv][b] = s;
        }
        __syncthreads();

        if (t < 32) {
            float tot = red2[0][t] + red2[1][t] + red2[2][t] + red2[3][t];
            float soma = K_ * tot;                      // sum of relu(K*z) = K * sum relu(z)
            out[(size_t)(b0 + t) * OUT_ + o] = fmaxf(K_ * (soma - QS_), 0.f);
        }
        __syncthreads();   // red[] is reused by the next tile's compute loop
    }
}

extern "C" void kernel_launch(void* const* d_in, const int* in_sizes, int n_in,
                              void* d_out, int out_size, void* d_ws, size_t ws_size,
                              hipStream_t stream) {
    const float* x  = (const float*)d_in[0];
    const float* W  = (const float*)d_in[1];
    const float* q  = (const float*)d_in[2];
    float* out      = (float*)d_out;

    dnm_kernel<<<dim3(OUT_), dim3(256), 0, stream>>>(x, W, q, out);
}